// Round 2
// baseline (4088.788 us; speedup 1.0000x reference)
//
#include <hip/hip_runtime.h>

// Problem constants
#define BQ 8
#define CQ 16
#define LQ 2048
#define NQ 2048
#define NPS 128      // nperseg
#define STEPQ 64     // step (50% overlap)
#define SQ 31        // segments per series
#define FQ 65        // rfft bins
#define KQ 32        // nref
#define EPSQ 1e-12f

// ---- workspace layout (bytes) ----
// tables (floats): [0,128) win | [128,1168) w128 (float2[520])
#define TAB_FLOATS 1168
#define XSPEC_OFF  6144ull                      // float2 [B][F][S][C] = 257920 float2
#define PXX_OFF    2069504ull                   // float [B][C][F] = 8320 floats
#define SCORES_OFF 2102784ull                   // float [B][C][N] = 262144 floats
#define TOPK_OFF   3151360ull                   // int [B][C][K] = 8192 ints

// ---- shared memory layout (float offsets) ----
#define OFF_WIN   0                              // 128
#define OFF_W128  128                            // float2[520] = 1040 floats
#define OFF_G     1168                           // float2[31*8*9=2232] = 4464 floats
#define OFF_Y     5632                           // float2[31*66] = 4092 floats (LD=66 for b128 align)
#define OFF_PYY   1168                           // overlays G (dead after stage2)
#define OFF_RED   1233                           // overlays G
#define SMEM_FLOATS 9724                         // 38896 B -> 4 blocks/CU

#define YLD 66

// 16th roots of unity (cos/sin of 2*pi*j/16), for constant-folded stage-1 radix-16
__device__ __constant__ const float COS16_[16] = {
    1.0f, 0.92387953251128675613f, 0.70710678118654752440f, 0.38268343236508977173f,
    0.0f, -0.38268343236508977173f, -0.70710678118654752440f, -0.92387953251128675613f,
    -1.0f, -0.92387953251128675613f, -0.70710678118654752440f, -0.38268343236508977173f,
    0.0f, 0.38268343236508977173f, 0.70710678118654752440f, 0.92387953251128675613f};
__device__ __constant__ const float SIN16_[16] = {
    0.0f, 0.38268343236508977173f, 0.70710678118654752440f, 0.92387953251128675613f,
    1.0f, 0.92387953251128675613f, 0.70710678118654752440f, 0.38268343236508977173f,
    0.0f, -0.38268343236508977173f, -0.70710678118654752440f, -0.92387953251128675613f,
    -1.0f, -0.92387953251128675613f, -0.70710678118654752440f, -0.38268343236508977173f};

__global__ void k_tables(float* __restrict__ gtab) {
    const int tid = threadIdx.x;
    const double PI2 = 6.283185307179586476925286766559;
    if (tid < 128) {
        gtab[tid] = (float)(0.5 - 0.5 * cos(PI2 * (double)tid / 128.0));
    }
    for (int j = tid; j < 520; j += 256) {
        int t1 = j / 65, k = j % 65;
        double a = PI2 * (double)(t1 * k) / 128.0;
        gtab[128 + 2 * j]     = (float)cos(a);
        gtab[128 + 2 * j + 1] = (float)(-sin(a));
    }
}

// Welch spectra of one length-2048 row into smem Y (float2 [31][YLD], valid cols 0..64).
// Stage 1 (radix-16, constant twiddles) reads global directly; mean via wave shuffles.
__device__ __forceinline__ void welch_spectra(const float* __restrict__ grow,
                                              const float* __restrict__ gtab,
                                              float* smem) {
    const int tid = threadIdx.x;
    float*  s_win = smem + OFF_WIN;
    float2* s_w   = (float2*)(smem + OFF_W128);
    float2* s_g   = (float2*)(smem + OFF_G);
    float2* s_y   = (float2*)(smem + OFF_Y);

    // stage tables global->LDS (coalesced, contiguous)
    for (int i = tid; i < TAB_FLOATS; i += 256) smem[i] = gtab[i];

    // ---- stage 1: per (s,t1) thread, 248 active ----
    const bool act = tid < SQ * 8;
    const int s = tid >> 3, t1 = tid & 7;
    float x[16];
    float sum = 0.f;
    if (act) {
        const float* rp = grow + s * STEPQ + t1;
#pragma unroll
        for (int t2 = 0; t2 < 16; ++t2) x[t2] = rp[8 * t2];
#pragma unroll
        for (int t2 = 0; t2 < 16; ++t2) sum += x[t2];
    }
    // segment mean: reduce across the 8 t1-lanes (lanes s*8..s*8+7, within one wave)
    sum += __shfl_xor(sum, 1, 64);
    sum += __shfl_xor(sum, 2, 64);
    sum += __shfl_xor(sum, 4, 64);
    const float mean = sum * (1.0f / 128.0f);

    __syncthreads();   // tables (s_win, s_w) now visible

    if (act) {
#pragma unroll
        for (int t2 = 0; t2 < 16; ++t2) x[t2] = (x[t2] - mean) * s_win[t1 + 8 * t2];
        // G[s][t1][m] = sum_t2 xw[t2] * e^{-2pi i m t2/16}, m=0..8 (constant twiddles)
#pragma unroll
        for (int m = 0; m < 9; ++m) {
            float gr = 0.f, gi = 0.f;
#pragma unroll
            for (int t2 = 0; t2 < 16; ++t2) {
                const int j = (m * t2) & 15;
                gr = fmaf(x[t2], COS16_[j], gr);
                gi = fmaf(x[t2], -SIN16_[j], gi);
            }
            s_g[tid * 9 + m] = make_float2(gr, gi);
        }
    }
    __syncthreads();

    // ---- stage 2: Y[s][k] = sum_{t1<8} e^{-2pi i t1 k/128} * G[s][t1][fold(k)] ----
    for (int i = tid; i < SQ * FQ; i += 256) {
        const int s2 = i / 65, k = i - 65 * s2;
        const int m = k & 15;
        const int mm = (m <= 8) ? m : 16 - m;
        const float sg = (m <= 8) ? 1.0f : -1.0f;   // conj for m>8 (real-input symmetry)
        float yr = 0.f, yi = 0.f;
        const float2* gp = s_g + (s2 * 8) * 9 + mm;
        const float2* wp = s_w + k;
#pragma unroll
        for (int t1i = 0; t1i < 8; ++t1i) {
            const float2 g = gp[t1i * 9];
            const float gi2 = g.y * sg;
            const float2 w = wp[t1i * 65];
            yr += w.x * g.x - w.y * gi2;
            yi += w.x * gi2 + w.y * g.x;
        }
        s_y[s2 * YLD + k] = make_float2(yr, yi);
    }
    __syncthreads();
}

// Target spectra: one block per (b,c). Writes Xspec [B][F][S][C] (float2) and Pxx [B][C][F].
__global__ __launch_bounds__(256, 4) void k_xspec(const float* __restrict__ tgt,
                                                  const float* __restrict__ gtab,
                                                  float2* __restrict__ xspec,
                                                  float* __restrict__ pxx) {
    __shared__ float smem[SMEM_FLOATS];
    const int blk = blockIdx.x;            // b*16 + c
    const int b = blk >> 4, c = blk & 15;
    welch_spectra(tgt + (size_t)blk * LQ, gtab, smem);
    const float2* s_y = (const float2*)(smem + OFF_Y);
    const int tid = threadIdx.x;
    for (int i = tid; i < SQ * FQ; i += 256) {
        const int s2 = i / 65, k = i - 65 * s2;
        xspec[((size_t)b * FQ + k) * (SQ * CQ) + s2 * CQ + c] = s_y[s2 * YLD + k];
    }
    if (tid < FQ) {
        float a = 0.f;
        for (int s = 0; s < SQ; ++s) {
            const float2 y = s_y[s * YLD + tid];
            a += y.x * y.x + y.y * y.y;
        }
        pxx[(size_t)blk * FQ + tid] = a * (1.0f / (float)SQ);
    }
}

// Score: one block per (b,n). Y spectra, Pyy, coherence vs 16 channels.
__global__ __launch_bounds__(256, 4) void k_score(const float* __restrict__ db,
                                                  const float* __restrict__ gtab,
                                                  const float2* __restrict__ xspec,
                                                  const float* __restrict__ pxx,
                                                  float* __restrict__ scores) {
    __shared__ float smem[SMEM_FLOATS];
    const int blk = blockIdx.x;            // b*2048 + n
    const int b = blk >> 11, n = blk & 2047;
    welch_spectra(db + (size_t)blk * LQ, gtab, smem);
    float* s_pyy = smem + OFF_PYY;         // overlays dead G
    float* s_red = smem + OFF_RED;
    const int tid = threadIdx.x;

    if (tid < FQ) {
        float a = 0.f;
        for (int s = 0; s < SQ; ++s) {
            const float2 y = ((const float2*)(smem + OFF_Y))[s * YLD + tid];
            a += y.x * y.x + y.y * y.y;
        }
        s_pyy[tid] = a * (1.0f / (float)SQ);
    }
    __syncthreads();

    const int c = tid & 15, g = tid >> 4;
    const int f0 = 4 * g;
    const float2* xb = xspec + (size_t)b * (FQ * SQ * CQ) + c;
    const float*  px = pxx + ((size_t)b * CQ + c) * FQ;

    float pr0 = 0.f, pi0 = 0.f, pr1 = 0.f, pi1 = 0.f;
    float pr2 = 0.f, pi2 = 0.f, pr3 = 0.f, pi3 = 0.f;
    float pr4 = 0.f, pi4 = 0.f;

    for (int s = 0; s < SQ; ++s) {
        // 4 consecutive bins via two 16B LDS reads (16-lane broadcast each)
        const float4* yp = (const float4*)(smem + OFF_Y + (size_t)(s * YLD + f0) * 2);
        const float4 ya = yp[0];            // y[f0], y[f0+1]
        const float4 yb = yp[1];            // y[f0+2], y[f0+3]
        const float2 x0 = xb[((f0 + 0) * SQ + s) * CQ];
        const float2 x1 = xb[((f0 + 1) * SQ + s) * CQ];
        const float2 x2 = xb[((f0 + 2) * SQ + s) * CQ];
        const float2 x3 = xb[((f0 + 3) * SQ + s) * CQ];
        pr0 += x0.x * ya.x + x0.y * ya.y;  pi0 += x0.y * ya.x - x0.x * ya.y;
        pr1 += x1.x * ya.z + x1.y * ya.w;  pi1 += x1.y * ya.z - x1.x * ya.w;
        pr2 += x2.x * yb.x + x2.y * yb.y;  pi2 += x2.y * yb.x - x2.x * yb.y;
        pr3 += x3.x * yb.z + x3.y * yb.w;  pi3 += x3.y * yb.z - x3.x * yb.w;
        if (g == 0) {                       // bin 64 handled by group 0
            const float2 y4 = ((const float2*)(smem + OFF_Y))[s * YLD + 64];
            const float2 x4 = xb[(64 * SQ + s) * CQ];
            pr4 += x4.x * y4.x + x4.y * y4.y;  pi4 += x4.y * y4.x - x4.x * y4.y;
        }
    }
    const float invS2 = 1.0f / ((float)SQ * (float)SQ);
    float acc = 0.f;
    acc += ((pr0 * pr0 + pi0 * pi0) * invS2) / (px[f0 + 0] * s_pyy[f0 + 0] + EPSQ);
    acc += ((pr1 * pr1 + pi1 * pi1) * invS2) / (px[f0 + 1] * s_pyy[f0 + 1] + EPSQ);
    acc += ((pr2 * pr2 + pi2 * pi2) * invS2) / (px[f0 + 2] * s_pyy[f0 + 2] + EPSQ);
    acc += ((pr3 * pr3 + pi3 * pi3) * invS2) / (px[f0 + 3] * s_pyy[f0 + 3] + EPSQ);
    if (g == 0)
        acc += ((pr4 * pr4 + pi4 * pi4) * invS2) / (px[64] * s_pyy[64] + EPSQ);

    s_red[tid] = acc;                       // tid = g*16 + c
    __syncthreads();
    if (tid < 16) {
        float a = 0.f;
#pragma unroll
        for (int gg = 0; gg < 16; ++gg) a += s_red[gg * 16 + tid];
        scores[((size_t)b * CQ + tid) * NQ + n] = a * (1.0f / (float)FQ);
    }
}

// Top-32 per (b,c) row, jax.lax.top_k semantics (descending, ties -> smallest index).
__global__ __launch_bounds__(256) void k_topk(const float* __restrict__ scores,
                                              int* __restrict__ topk) {
    __shared__ float sv[NQ];
    __shared__ float rv[4];
    __shared__ int   ri[4];
    const int blk = blockIdx.x, tid = threadIdx.x;
    const float* row = scores + (size_t)blk * NQ;
    for (int i = tid; i < NQ; i += 256) sv[i] = row[i];
    __syncthreads();
    for (int k = 0; k < KQ; ++k) {
        float best = -3.402823466e38f;
        int bi = 0x7fffffff;
        for (int j = tid; j < NQ; j += 256) {
            const float v = sv[j];
            if (v > best) { best = v; bi = j; }   // ascending j: strict > keeps smallest idx
        }
        // wave-level butterfly (no barriers)
#pragma unroll
        for (int off = 1; off < 64; off <<= 1) {
            const float ov = __shfl_xor(best, off, 64);
            const int   oi = __shfl_xor(bi, off, 64);
            if (ov > best || (ov == best && oi < bi)) { best = ov; bi = oi; }
        }
        if ((tid & 63) == 0) { rv[tid >> 6] = best; ri[tid >> 6] = bi; }
        __syncthreads();
        if (tid == 0) {
            float bv = rv[0]; int bj = ri[0];
#pragma unroll
            for (int w = 1; w < 4; ++w) {
                if (rv[w] > bv || (rv[w] == bv && ri[w] < bj)) { bv = rv[w]; bj = ri[w]; }
            }
            topk[blk * KQ + k] = bj;
            sv[bj] = -3.402823466e38f;
        }
        __syncthreads();
    }
}

// Gather: one block per output row (b, c*32+k) -> copy DB row (2048 floats) via float4.
__global__ __launch_bounds__(256) void k_gather(const float* __restrict__ db,
                                                const int* __restrict__ topk,
                                                float* __restrict__ out) {
    const int row = blockIdx.x;               // b*512 + c*32 + k
    const int b = row >> 9;
    const int idx = topk[row];
    const float4* src = (const float4*)(db + ((size_t)(b * NQ + idx)) * LQ);
    float4* dst = (float4*)(out + (size_t)row * LQ);
    const int tid = threadIdx.x;
    dst[tid] = src[tid];
    dst[tid + 256] = src[tid + 256];
}

extern "C" void kernel_launch(void* const* d_in, const int* in_sizes, int n_in,
                              void* d_out, int out_size, void* d_ws, size_t ws_size,
                              hipStream_t stream) {
    const float* tgt = (const float*)d_in[0];   // [8,16,2048]
    const float* db  = (const float*)d_in[1];   // [8,2048,2048]
    float* out = (float*)d_out;                 // [8,512,2048]
    char* ws = (char*)d_ws;

    float*  gtab   = (float*)(ws);
    float2* xspec  = (float2*)(ws + XSPEC_OFF);
    float*  pxx    = (float*)(ws + PXX_OFF);
    float*  scores = (float*)(ws + SCORES_OFF);
    int*    topk   = (int*)(ws + TOPK_OFF);

    hipLaunchKernelGGL(k_tables, dim3(1),            dim3(256), 0, stream, gtab);
    hipLaunchKernelGGL(k_xspec,  dim3(BQ * CQ),      dim3(256), 0, stream, tgt, gtab, xspec, pxx);
    hipLaunchKernelGGL(k_score,  dim3(BQ * NQ),      dim3(256), 0, stream, db, gtab, xspec, pxx, scores);
    hipLaunchKernelGGL(k_topk,   dim3(BQ * CQ),      dim3(256), 0, stream, scores, topk);
    hipLaunchKernelGGL(k_gather, dim3(BQ * CQ * KQ), dim3(256), 0, stream, db, topk, out);
}

// Round 3
// 542.856 us; speedup vs baseline: 7.5320x; 7.5320x over previous
//
#include <hip/hip_runtime.h>

// Problem constants
#define BQ 8
#define CQ 16
#define LQ 2048
#define NQ 2048
#define NPS 128      // nperseg
#define STEPQ 64     // step (50% overlap)
#define SQ 31        // segments per series
#define FQ 65        // rfft bins
#define KQ 32        // nref
#define EPSQ 1e-12f

// ---- workspace layout (bytes) ----
// tables (floats): [0,128) win | [128,1168) w128 (float2[520])
#define TAB_FLOATS 1168
#define XSPEC_OFF  6144ull                      // float2 [B][F][S][C] = 257920 float2
#define PXX_OFF    2069504ull                   // float [B][C][F] = 8320 floats
#define SCORES_OFF 2102784ull                   // float [B][C][N] = 262144 floats
#define TOPK_OFF   3151360ull                   // int [B][C][K] = 8192 ints

// ---- shared memory layout (float offsets) ----
#define OFF_WIN   0                              // 128
#define OFF_W128  128                            // float2[520] = 1040 floats
#define OFF_G     1168                           // float2[31*8*9=2232] = 4464 floats
#define OFF_Y     5632                           // float2[31*66] = 4092 floats (LD=66 for b128 align)
#define OFF_PYY   1168                           // overlays G (dead after stage2)
#define OFF_RED   1233                           // overlays G
#define SMEM_FLOATS 9724                         // 38896 B -> 4 blocks/CU (LDS-limited)

#define YLD 66

// 16th roots of unity (cos/sin of 2*pi*j/16), for constant-folded stage-1 radix-16
__device__ __constant__ const float COS16_[16] = {
    1.0f, 0.92387953251128675613f, 0.70710678118654752440f, 0.38268343236508977173f,
    0.0f, -0.38268343236508977173f, -0.70710678118654752440f, -0.92387953251128675613f,
    -1.0f, -0.92387953251128675613f, -0.70710678118654752440f, -0.38268343236508977173f,
    0.0f, 0.38268343236508977173f, 0.70710678118654752440f, 0.92387953251128675613f};
__device__ __constant__ const float SIN16_[16] = {
    0.0f, 0.38268343236508977173f, 0.70710678118654752440f, 0.92387953251128675613f,
    1.0f, 0.92387953251128675613f, 0.70710678118654752440f, 0.38268343236508977173f,
    0.0f, -0.38268343236508977173f, -0.70710678118654752440f, -0.92387953251128675613f,
    -1.0f, -0.92387953251128675613f, -0.70710678118654752440f, -0.38268343236508977173f};

__global__ void k_tables(float* __restrict__ gtab) {
    const int tid = threadIdx.x;
    const double PI2 = 6.283185307179586476925286766559;
    if (tid < 128) {
        gtab[tid] = (float)(0.5 - 0.5 * cos(PI2 * (double)tid / 128.0));
    }
    for (int j = tid; j < 520; j += 256) {
        int t1 = j / 65, k = j % 65;
        double a = PI2 * (double)(t1 * k) / 128.0;
        gtab[128 + 2 * j]     = (float)cos(a);
        gtab[128 + 2 * j + 1] = (float)(-sin(a));
    }
}

// Welch spectra of one length-2048 row into smem Y (float2 [31][YLD], valid cols 0..64).
// Stage 1 (radix-16, constant twiddles) reads global directly; mean via wave shuffles.
__device__ __forceinline__ void welch_spectra(const float* __restrict__ grow,
                                              const float* __restrict__ gtab,
                                              float* smem) {
    const int tid = threadIdx.x;
    float*  s_win = smem + OFF_WIN;
    float2* s_w   = (float2*)(smem + OFF_W128);
    float2* s_g   = (float2*)(smem + OFF_G);
    float2* s_y   = (float2*)(smem + OFF_Y);

    // stage tables global->LDS (coalesced, contiguous)
    for (int i = tid; i < TAB_FLOATS; i += 256) smem[i] = gtab[i];

    // ---- stage 1: per (s,t1) thread, 248 active ----
    const bool act = tid < SQ * 8;
    const int s = tid >> 3, t1 = tid & 7;
    float x[16];
    float sum = 0.f;
    if (act) {
        const float* rp = grow + s * STEPQ + t1;
#pragma unroll
        for (int t2 = 0; t2 < 16; ++t2) x[t2] = rp[8 * t2];
#pragma unroll
        for (int t2 = 0; t2 < 16; ++t2) sum += x[t2];
    }
    // segment mean: reduce across the 8 t1-lanes (lanes s*8..s*8+7, within one wave)
    sum += __shfl_xor(sum, 1, 64);
    sum += __shfl_xor(sum, 2, 64);
    sum += __shfl_xor(sum, 4, 64);
    const float mean = sum * (1.0f / 128.0f);

    __syncthreads();   // tables (s_win, s_w) now visible

    if (act) {
#pragma unroll
        for (int t2 = 0; t2 < 16; ++t2) x[t2] = (x[t2] - mean) * s_win[t1 + 8 * t2];
        // G[s][t1][m] = sum_t2 xw[t2] * e^{-2pi i m t2/16}, m=0..8 (constant twiddles)
#pragma unroll
        for (int m = 0; m < 9; ++m) {
            float gr = 0.f, gi = 0.f;
#pragma unroll
            for (int t2 = 0; t2 < 16; ++t2) {
                const int j = (m * t2) & 15;
                gr = fmaf(x[t2], COS16_[j], gr);
                gi = fmaf(x[t2], -SIN16_[j], gi);
            }
            s_g[tid * 9 + m] = make_float2(gr, gi);
        }
    }
    __syncthreads();

    // ---- stage 2: Y[s][k] = sum_{t1<8} e^{-2pi i t1 k/128} * G[s][t1][fold(k)] ----
    for (int i = tid; i < SQ * FQ; i += 256) {
        const int s2 = i / 65, k = i - 65 * s2;
        const int m = k & 15;
        const int mm = (m <= 8) ? m : 16 - m;
        const float sg = (m <= 8) ? 1.0f : -1.0f;   // conj for m>8 (real-input symmetry)
        float yr = 0.f, yi = 0.f;
        const float2* gp = s_g + (s2 * 8) * 9 + mm;
        const float2* wp = s_w + k;
#pragma unroll
        for (int t1i = 0; t1i < 8; ++t1i) {
            const float2 g = gp[t1i * 9];
            const float gi2 = g.y * sg;
            const float2 w = wp[t1i * 65];
            yr += w.x * g.x - w.y * gi2;
            yi += w.x * gi2 + w.y * g.x;
        }
        s_y[s2 * YLD + k] = make_float2(yr, yi);
    }
    __syncthreads();
}

// Target spectra: one block per (b,c). Writes Xspec [B][F][S][C] (float2) and Pxx [B][C][F].
__global__ __launch_bounds__(256) void k_xspec(const float* __restrict__ tgt,
                                               const float* __restrict__ gtab,
                                               float2* __restrict__ xspec,
                                               float* __restrict__ pxx) {
    __shared__ float smem[SMEM_FLOATS];
    const int blk = blockIdx.x;            // b*16 + c
    const int b = blk >> 4, c = blk & 15;
    welch_spectra(tgt + (size_t)blk * LQ, gtab, smem);
    const float2* s_y = (const float2*)(smem + OFF_Y);
    const int tid = threadIdx.x;
    for (int i = tid; i < SQ * FQ; i += 256) {
        const int s2 = i / 65, k = i - 65 * s2;
        xspec[((size_t)b * FQ + k) * (SQ * CQ) + s2 * CQ + c] = s_y[s2 * YLD + k];
    }
    if (tid < FQ) {
        float a = 0.f;
        for (int s = 0; s < SQ; ++s) {
            const float2 y = s_y[s * YLD + tid];
            a += y.x * y.x + y.y * y.y;
        }
        pxx[(size_t)blk * FQ + tid] = a * (1.0f / (float)SQ);
    }
}

// Score: one block per (b,n). Y spectra, Pyy, coherence vs 16 channels.
__global__ __launch_bounds__(256) void k_score(const float* __restrict__ db,
                                               const float* __restrict__ gtab,
                                               const float2* __restrict__ xspec,
                                               const float* __restrict__ pxx,
                                               float* __restrict__ scores) {
    __shared__ float smem[SMEM_FLOATS];
    const int blk = blockIdx.x;            // b*2048 + n
    const int b = blk >> 11, n = blk & 2047;
    welch_spectra(db + (size_t)blk * LQ, gtab, smem);
    float* s_pyy = smem + OFF_PYY;         // overlays dead G
    float* s_red = smem + OFF_RED;
    const int tid = threadIdx.x;

    if (tid < FQ) {
        float a = 0.f;
        for (int s = 0; s < SQ; ++s) {
            const float2 y = ((const float2*)(smem + OFF_Y))[s * YLD + tid];
            a += y.x * y.x + y.y * y.y;
        }
        s_pyy[tid] = a * (1.0f / (float)SQ);
    }
    __syncthreads();

    const int c = tid & 15, g = tid >> 4;
    const int f0 = 4 * g;
    const float2* xb = xspec + (size_t)b * (FQ * SQ * CQ) + c;
    const float*  px = pxx + ((size_t)b * CQ + c) * FQ;

    // main loop: bins f0..f0+3 (64 bins total); bin 64 in a post-loop (g==0 only)
    float pr0 = 0.f, pi0 = 0.f, pr1 = 0.f, pi1 = 0.f;
    float pr2 = 0.f, pi2 = 0.f, pr3 = 0.f, pi3 = 0.f;

    for (int s = 0; s < SQ; ++s) {
        // 4 consecutive bins via two 16B LDS reads (16-lane broadcast each)
        const float4* yp = (const float4*)(smem + OFF_Y + (size_t)(s * YLD + f0) * 2);
        const float4 ya = yp[0];            // y[f0], y[f0+1]
        const float4 yb = yp[1];            // y[f0+2], y[f0+3]
        const float2 x0 = xb[((f0 + 0) * SQ + s) * CQ];
        const float2 x1 = xb[((f0 + 1) * SQ + s) * CQ];
        const float2 x2 = xb[((f0 + 2) * SQ + s) * CQ];
        const float2 x3 = xb[((f0 + 3) * SQ + s) * CQ];
        pr0 += x0.x * ya.x + x0.y * ya.y;  pi0 += x0.y * ya.x - x0.x * ya.y;
        pr1 += x1.x * ya.z + x1.y * ya.w;  pi1 += x1.y * ya.z - x1.x * ya.w;
        pr2 += x2.x * yb.x + x2.y * yb.y;  pi2 += x2.y * yb.x - x2.x * yb.y;
        pr3 += x3.x * yb.z + x3.y * yb.w;  pi3 += x3.y * yb.z - x3.x * yb.w;
    }
    const float invS2 = 1.0f / ((float)SQ * (float)SQ);
    float acc = 0.f;
    acc += ((pr0 * pr0 + pi0 * pi0) * invS2) / (px[f0 + 0] * s_pyy[f0 + 0] + EPSQ);
    acc += ((pr1 * pr1 + pi1 * pi1) * invS2) / (px[f0 + 1] * s_pyy[f0 + 1] + EPSQ);
    acc += ((pr2 * pr2 + pi2 * pi2) * invS2) / (px[f0 + 2] * s_pyy[f0 + 2] + EPSQ);
    acc += ((pr3 * pr3 + pi3 * pi3) * invS2) / (px[f0 + 3] * s_pyy[f0 + 3] + EPSQ);

    if (g == 0) {                            // bin 64 tail, 16 threads
        float pr4 = 0.f, pi4 = 0.f;
        for (int s = 0; s < SQ; ++s) {
            const float2 y4 = ((const float2*)(smem + OFF_Y))[s * YLD + 64];
            const float2 x4 = xb[(64 * SQ + s) * CQ];
            pr4 += x4.x * y4.x + x4.y * y4.y;  pi4 += x4.y * y4.x - x4.x * y4.y;
        }
        acc += ((pr4 * pr4 + pi4 * pi4) * invS2) / (px[64] * s_pyy[64] + EPSQ);
    }

    s_red[tid] = acc;                       // tid = g*16 + c
    __syncthreads();
    if (tid < 16) {
        float a = 0.f;
#pragma unroll
        for (int gg = 0; gg < 16; ++gg) a += s_red[gg * 16 + tid];
        scores[((size_t)b * CQ + tid) * NQ + n] = a * (1.0f / (float)FQ);
    }
}

// Top-32 per (b,c) row, jax.lax.top_k semantics (descending, ties -> smallest index).
__global__ __launch_bounds__(256) void k_topk(const float* __restrict__ scores,
                                              int* __restrict__ topk) {
    __shared__ float sv[NQ];
    __shared__ float rv[4];
    __shared__ int   ri[4];
    const int blk = blockIdx.x, tid = threadIdx.x;
    const float* row = scores + (size_t)blk * NQ;
    for (int i = tid; i < NQ; i += 256) sv[i] = row[i];
    __syncthreads();
    for (int k = 0; k < KQ; ++k) {
        float best = -3.402823466e38f;
        int bi = 0x7fffffff;
        for (int j = tid; j < NQ; j += 256) {
            const float v = sv[j];
            if (v > best) { best = v; bi = j; }   // ascending j: strict > keeps smallest idx
        }
        // wave-level butterfly (no barriers)
#pragma unroll
        for (int off = 1; off < 64; off <<= 1) {
            const float ov = __shfl_xor(best, off, 64);
            const int   oi = __shfl_xor(bi, off, 64);
            if (ov > best || (ov == best && oi < bi)) { best = ov; bi = oi; }
        }
        if ((tid & 63) == 0) { rv[tid >> 6] = best; ri[tid >> 6] = bi; }
        __syncthreads();
        if (tid == 0) {
            float bv = rv[0]; int bj = ri[0];
#pragma unroll
            for (int w = 1; w < 4; ++w) {
                if (rv[w] > bv || (rv[w] == bv && ri[w] < bj)) { bv = rv[w]; bj = ri[w]; }
            }
            topk[blk * KQ + k] = bj;
            sv[bj] = -3.402823466e38f;
        }
        __syncthreads();
    }
}

// Gather: one block per output row (b, c*32+k) -> copy DB row (2048 floats) via float4.
__global__ __launch_bounds__(256) void k_gather(const float* __restrict__ db,
                                                const int* __restrict__ topk,
                                                float* __restrict__ out) {
    const int row = blockIdx.x;               // b*512 + c*32 + k
    const int b = row >> 9;
    const int idx = topk[row];
    const float4* src = (const float4*)(db + ((size_t)(b * NQ + idx)) * LQ);
    float4* dst = (float4*)(out + (size_t)row * LQ);
    const int tid = threadIdx.x;
    dst[tid] = src[tid];
    dst[tid + 256] = src[tid + 256];
}

extern "C" void kernel_launch(void* const* d_in, const int* in_sizes, int n_in,
                              void* d_out, int out_size, void* d_ws, size_t ws_size,
                              hipStream_t stream) {
    const float* tgt = (const float*)d_in[0];   // [8,16,2048]
    const float* db  = (const float*)d_in[1];   // [8,2048,2048]
    float* out = (float*)d_out;                 // [8,512,2048]
    char* ws = (char*)d_ws;

    float*  gtab   = (float*)(ws);
    float2* xspec  = (float2*)(ws + XSPEC_OFF);
    float*  pxx    = (float*)(ws + PXX_OFF);
    float*  scores = (float*)(ws + SCORES_OFF);
    int*    topk   = (int*)(ws + TOPK_OFF);

    hipLaunchKernelGGL(k_tables, dim3(1),            dim3(256), 0, stream, gtab);
    hipLaunchKernelGGL(k_xspec,  dim3(BQ * CQ),      dim3(256), 0, stream, tgt, gtab, xspec, pxx);
    hipLaunchKernelGGL(k_score,  dim3(BQ * NQ),      dim3(256), 0, stream, db, gtab, xspec, pxx, scores);
    hipLaunchKernelGGL(k_topk,   dim3(BQ * CQ),      dim3(256), 0, stream, scores, topk);
    hipLaunchKernelGGL(k_gather, dim3(BQ * CQ * KQ), dim3(256), 0, stream, db, topk, out);
}

// Round 4
// 507.362 us; speedup vs baseline: 8.0589x; 1.0700x over previous
//
#include <hip/hip_runtime.h>

// Problem constants
#define BQ 8
#define CQ 16
#define LQ 2048
#define NQ 2048
#define NPS 128      // nperseg
#define STEPQ 64     // step (50% overlap)
#define SQ 31        // segments per series
#define FQ 65        // rfft bins
#define KQ 32        // nref
#define EPSQ 1e-12f

// ---- workspace layout (bytes) ----
#define XSPEC_OFF  0ull                          // float2 [B][F][S][C] = 257920 float2 (2063360 B)
#define PXX_OFF    2063360ull                    // float [B][C][F] = 8320 floats
#define SCORES_OFF 2096640ull                    // float [B][C][N] = 262144 floats (ends 3145216)

// ---- shared memory layout (float offsets) ----
#define YLD 66
#define OFF_Y     0                              // float2[31*66] = 4092 floats (LD=66, b128-aligned)
#define OFF_PYY   4092                           // 65
#define OFF_RED   4157                           // 256
#define SMEM_FLOATS 4413                         // 17652 B -> 8 blocks/CU (wave-capped)

// 16th roots of unity for constant-folded stage-1 radix-16 (indices are compile-time)
__device__ __constant__ const float COS16_[16] = {
    1.0f, 0.92387953251128675613f, 0.70710678118654752440f, 0.38268343236508977173f,
    0.0f, -0.38268343236508977173f, -0.70710678118654752440f, -0.92387953251128675613f,
    -1.0f, -0.92387953251128675613f, -0.70710678118654752440f, -0.38268343236508977173f,
    0.0f, 0.38268343236508977173f, 0.70710678118654752440f, 0.92387953251128675613f};
__device__ __constant__ const float SIN16_[16] = {
    0.0f, 0.38268343236508977173f, 0.70710678118654752440f, 0.92387953251128675613f,
    1.0f, 0.92387953251128675613f, 0.70710678118654752440f, 0.38268343236508977173f,
    0.0f, -0.38268343236508977173f, -0.70710678118654752440f, -0.92387953251128675613f,
    -1.0f, -0.92387953251128675613f, -0.70710678118654752440f, -0.38268343236508977173f};

// stage-A butterfly twiddles W8^{t1-4} for t1>=4, identity for t1<4
__device__ __constant__ const float WA_R[8] = {1.f, 1.f, 1.f, 1.f,
    1.f, 0.70710678118654752440f, 0.f, -0.70710678118654752440f};
__device__ __constant__ const float WA_I[8] = {0.f, 0.f, 0.f, 0.f,
    0.f, -0.70710678118654752440f, -1.f, -0.70710678118654752440f};
__device__ __constant__ const int BR3_[8] = {0, 4, 2, 6, 1, 5, 3, 7};

#define TWOPI_128 0.049087385212340519350978802863742f   // 2*pi/128

// Welch spectra of one length-2048 row into smem Y (float2 [31][YLD], cols 0..64).
// Stage 1: radix-16 per (s,t1) thread from global, mean via lane shuffles, window in regs.
// Stage 2: 8-point DIF DFT across the 8 t1-lanes via shfl_xor (no LDS intermediate).
__device__ __forceinline__ void welch_spectra(const float* __restrict__ grow,
                                              float* smem) {
    const int tid = threadIdx.x;
    float2* s_y = (float2*)(smem + OFF_Y);

    const bool act = tid < SQ * 8;
    const int s = tid >> 3, t1 = tid & 7;

    float x[16];
    float sum = 0.f;
    if (act) {
        const float* rp = grow + s * STEPQ + t1;
#pragma unroll
        for (int t2 = 0; t2 < 16; ++t2) x[t2] = rp[8 * t2];
#pragma unroll
        for (int t2 = 0; t2 < 16; ++t2) sum += x[t2];
    }
    // segment mean across the 8 t1-lanes (contiguous lanes, same wave)
    sum += __shfl_xor(sum, 1, 64);
    sum += __shfl_xor(sum, 2, 64);
    sum += __shfl_xor(sum, 4, 64);
    const float mean = sum * (1.0f / 128.0f);

    float2 G[9];
    if (act) {
#pragma unroll
        for (int t2 = 0; t2 < 16; ++t2) {
            const float a = (float)(t1 + 8 * t2) * TWOPI_128;
            x[t2] = (x[t2] - mean) * (0.5f - 0.5f * __cosf(a));
        }
#pragma unroll
        for (int m = 0; m < 9; ++m) {
            float gr = 0.f, gi = 0.f;
#pragma unroll
            for (int t2 = 0; t2 < 16; ++t2) {
                const int j = (m * t2) & 15;
                gr = fmaf(x[t2], COS16_[j], gr);
                gi = fmaf(x[t2], -SIN16_[j], gi);
            }
            G[m] = make_float2(gr, gi);
        }
    }

    // per-lane butterfly constants
    const float s1 = (t1 & 4) ? -1.f : 1.f;
    const float s2 = (t1 & 2) ? -1.f : 1.f;
    const float s3 = (t1 & 1) ? -1.f : 1.f;
    const float war = WA_R[t1], wai = WA_I[t1];
    const bool q3 = (t1 & 3) == 3;
    const int kbase = 16 * BR3_[t1];

    // incremental H-twiddle rotation: w(m') = e^{-2pi i t1 m'/128}
    float cr, ci;
    __sincosf((float)t1 * TWOPI_128, &ci, &cr);   // ci=sin, cr=cos
    ci = -ci;
    float wr = 1.f, wi = 0.f;

    if (act) {
#pragma unroll
        for (int mp = 0; mp < 16; ++mp) {
            const int mm = (mp <= 8) ? mp : 16 - mp;
            const float sg = (mp <= 8) ? 1.f : -1.f;   // conj(G) for m'>8 (real input)
            const float gr = G[mm].x, gi = sg * G[mm].y;
            float hr = wr * gr - wi * gi;
            float hi = wr * gi + wi * gr;
            // stage A: xor 4, twiddle W8^{t1-4} on upper lanes
            float orr = __shfl_xor(hr, 4, 64), oi = __shfl_xor(hi, 4, 64);
            float vr = fmaf(s1, hr, orr), vi = fmaf(s1, hi, oi);
            hr = vr * war - vi * wai;
            hi = vr * wai + vi * war;
            // stage B: xor 2, twiddle -i on q==3 lanes
            orr = __shfl_xor(hr, 2, 64); oi = __shfl_xor(hi, 2, 64);
            vr = fmaf(s2, hr, orr); vi = fmaf(s2, hi, oi);
            hr = q3 ? vi : vr;
            hi = q3 ? -vr : vi;
            // stage C: xor 1
            orr = __shfl_xor(hr, 1, 64); oi = __shfl_xor(hi, 1, 64);
            vr = fmaf(s3, hr, orr); vi = fmaf(s3, hi, oi);
            const int k = mp + kbase;                 // lane t1 holds output j=br3(t1)
            if (k <= 64) s_y[s * YLD + k] = make_float2(vr, vi);
            // rotate twiddle
            const float nwr = wr * cr - wi * ci;
            wi = wr * ci + wi * cr;
            wr = nwr;
        }
    }
    __syncthreads();
}

// Target spectra: one block per (b,c). Writes Xspec [B][F][S][C] (float2) and Pxx [B][C][F].
__global__ __launch_bounds__(256) void k_xspec(const float* __restrict__ tgt,
                                               float2* __restrict__ xspec,
                                               float* __restrict__ pxx) {
    __shared__ float smem[SMEM_FLOATS];
    const int blk = blockIdx.x;            // b*16 + c
    const int b = blk >> 4, c = blk & 15;
    welch_spectra(tgt + (size_t)blk * LQ, smem);
    const float2* s_y = (const float2*)(smem + OFF_Y);
    const int tid = threadIdx.x;
    for (int i = tid; i < SQ * FQ; i += 256) {
        const int s2 = i / 65, k = i - 65 * s2;
        xspec[((size_t)b * FQ + k) * (SQ * CQ) + s2 * CQ + c] = s_y[s2 * YLD + k];
    }
    if (tid < FQ) {
        float a = 0.f;
        for (int s = 0; s < SQ; ++s) {
            const float2 y = s_y[s * YLD + tid];
            a += y.x * y.x + y.y * y.y;
        }
        pxx[(size_t)blk * FQ + tid] = a * (1.0f / (float)SQ);
    }
}

// Score: one block per (b,n). Y spectra, Pyy, coherence vs 16 channels.
__global__ __launch_bounds__(256) void k_score(const float* __restrict__ db,
                                               const float2* __restrict__ xspec,
                                               const float* __restrict__ pxx,
                                               float* __restrict__ scores) {
    __shared__ float smem[SMEM_FLOATS];
    const int blk = blockIdx.x;            // b*2048 + n
    const int b = blk >> 11, n = blk & 2047;
    welch_spectra(db + (size_t)blk * LQ, smem);
    float* s_pyy = smem + OFF_PYY;
    float* s_red = smem + OFF_RED;
    const int tid = threadIdx.x;

    if (tid < FQ) {
        float a = 0.f;
        for (int s = 0; s < SQ; ++s) {
            const float2 y = ((const float2*)(smem + OFF_Y))[s * YLD + tid];
            a += y.x * y.x + y.y * y.y;
        }
        s_pyy[tid] = a * (1.0f / (float)SQ);
    }
    __syncthreads();

    const int c = tid & 15, g = tid >> 4;
    const int f0 = 4 * g;
    const float2* xb = xspec + (size_t)b * (FQ * SQ * CQ) + c;
    const float*  px = pxx + ((size_t)b * CQ + c) * FQ;

    // main loop: bins f0..f0+3; bin 64 in a post-loop (g==0 only)
    float pr0 = 0.f, pi0 = 0.f, pr1 = 0.f, pi1 = 0.f;
    float pr2 = 0.f, pi2 = 0.f, pr3 = 0.f, pi3 = 0.f;

    for (int s = 0; s < SQ; ++s) {
        const float4* yp = (const float4*)(smem + OFF_Y + (size_t)(s * YLD + f0) * 2);
        const float4 ya = yp[0];            // y[f0], y[f0+1]
        const float4 yb = yp[1];            // y[f0+2], y[f0+3]
        const float2 x0 = xb[((f0 + 0) * SQ + s) * CQ];
        const float2 x1 = xb[((f0 + 1) * SQ + s) * CQ];
        const float2 x2 = xb[((f0 + 2) * SQ + s) * CQ];
        const float2 x3 = xb[((f0 + 3) * SQ + s) * CQ];
        pr0 += x0.x * ya.x + x0.y * ya.y;  pi0 += x0.y * ya.x - x0.x * ya.y;
        pr1 += x1.x * ya.z + x1.y * ya.w;  pi1 += x1.y * ya.z - x1.x * ya.w;
        pr2 += x2.x * yb.x + x2.y * yb.y;  pi2 += x2.y * yb.x - x2.x * yb.y;
        pr3 += x3.x * yb.z + x3.y * yb.w;  pi3 += x3.y * yb.z - x3.x * yb.w;
    }
    const float invS2 = 1.0f / ((float)SQ * (float)SQ);
    float acc = 0.f;
    acc += ((pr0 * pr0 + pi0 * pi0) * invS2) / (px[f0 + 0] * s_pyy[f0 + 0] + EPSQ);
    acc += ((pr1 * pr1 + pi1 * pi1) * invS2) / (px[f0 + 1] * s_pyy[f0 + 1] + EPSQ);
    acc += ((pr2 * pr2 + pi2 * pi2) * invS2) / (px[f0 + 2] * s_pyy[f0 + 2] + EPSQ);
    acc += ((pr3 * pr3 + pi3 * pi3) * invS2) / (px[f0 + 3] * s_pyy[f0 + 3] + EPSQ);

    if (g == 0) {                            // bin 64 tail, 16 threads
        float pr4 = 0.f, pi4 = 0.f;
        for (int s = 0; s < SQ; ++s) {
            const float2 y4 = ((const float2*)(smem + OFF_Y))[s * YLD + 64];
            const float2 x4 = xb[(64 * SQ + s) * CQ];
            pr4 += x4.x * y4.x + x4.y * y4.y;  pi4 += x4.y * y4.x - x4.x * y4.y;
        }
        acc += ((pr4 * pr4 + pi4 * pi4) * invS2) / (px[64] * s_pyy[64] + EPSQ);
    }

    s_red[tid] = acc;                       // tid = g*16 + c
    __syncthreads();
    if (tid < 16) {
        float a = 0.f;
#pragma unroll
        for (int gg = 0; gg < 16; ++gg) a += s_red[gg * 16 + tid];
        scores[((size_t)b * CQ + tid) * NQ + n] = a * (1.0f / (float)FQ);
    }
}

// Fused top-32 + gather per (b,c) row. jax.lax.top_k semantics (desc, ties->lowest idx).
__global__ __launch_bounds__(256) void k_topk_gather(const float* __restrict__ scores,
                                                     const float* __restrict__ db,
                                                     float* __restrict__ out) {
    __shared__ float sv[NQ];
    __shared__ float rv[4];
    __shared__ int   ri[4];
    __shared__ int   sel[KQ];
    const int blk = blockIdx.x, tid = threadIdx.x;
    const int b = blk >> 4;
    const float* row = scores + (size_t)blk * NQ;
    for (int i = tid; i < NQ; i += 256) sv[i] = row[i];
    __syncthreads();
    for (int k = 0; k < KQ; ++k) {
        float best = -3.402823466e38f;
        int bi = 0x7fffffff;
        for (int j = tid; j < NQ; j += 256) {
            const float v = sv[j];
            if (v > best) { best = v; bi = j; }   // ascending j: strict > keeps smallest idx
        }
#pragma unroll
        for (int off = 1; off < 64; off <<= 1) {
            const float ov = __shfl_xor(best, off, 64);
            const int   oi = __shfl_xor(bi, off, 64);
            if (ov > best || (ov == best && oi < bi)) { best = ov; bi = oi; }
        }
        if ((tid & 63) == 0) { rv[tid >> 6] = best; ri[tid >> 6] = bi; }
        __syncthreads();
        if (tid == 0) {
            float bv = rv[0]; int bj = ri[0];
#pragma unroll
            for (int w = 1; w < 4; ++w) {
                if (rv[w] > bv || (rv[w] == bv && ri[w] < bj)) { bv = rv[w]; bj = ri[w]; }
            }
            sel[k] = bj;
            sv[bj] = -3.402823466e38f;
        }
        __syncthreads();
    }
    // gather: copy 32 selected rows (8 KB each) via float4
    const float4* dbv = (const float4*)(db + (size_t)b * NQ * LQ);
    float4* outv = (float4*)(out + (size_t)blk * KQ * LQ);
    for (int r = 0; r < KQ; ++r) {
        const int idx = sel[r];
        const float4* src = dbv + (size_t)idx * (LQ / 4);
        float4* dst = outv + (size_t)r * (LQ / 4);
        dst[tid] = src[tid];
        dst[tid + 256] = src[tid + 256];
    }
}

extern "C" void kernel_launch(void* const* d_in, const int* in_sizes, int n_in,
                              void* d_out, int out_size, void* d_ws, size_t ws_size,
                              hipStream_t stream) {
    const float* tgt = (const float*)d_in[0];   // [8,16,2048]
    const float* db  = (const float*)d_in[1];   // [8,2048,2048]
    float* out = (float*)d_out;                 // [8,512,2048]
    char* ws = (char*)d_ws;

    float2* xspec  = (float2*)(ws + XSPEC_OFF);
    float*  pxx    = (float*)(ws + PXX_OFF);
    float*  scores = (float*)(ws + SCORES_OFF);

    hipLaunchKernelGGL(k_xspec,       dim3(BQ * CQ), dim3(256), 0, stream, tgt, xspec, pxx);
    hipLaunchKernelGGL(k_score,       dim3(BQ * NQ), dim3(256), 0, stream, db, xspec, pxx, scores);
    hipLaunchKernelGGL(k_topk_gather, dim3(BQ * CQ), dim3(256), 0, stream, scores, db, out);
}